// Round 4
// baseline (5307.290 us; speedup 1.0000x reference)
//
#include <hip/hip_runtime.h>
#include <cstddef>

// ---------------------------------------------------------------------------
// VQ-VAE forward, fp32 direct conv. Round 4: 2x2 outputs/thread x 32 co
// (1:4 LDS:FMA), register-prefetch software pipeline on all conv staging,
// full-batch enc0, 2-pos quantize with float4 codebook reads.
// ---------------------------------------------------------------------------

typedef float v4f __attribute__((ext_vector_type(4)));

__device__ __forceinline__ void fma4(v4f& a, float p, const v4f& w) {
    a.x = fmaf(p, w.x, a.x); a.y = fmaf(p, w.y, a.y);
    a.z = fmaf(p, w.z, a.z); a.w = fmaf(p, w.w, a.w);
}

// Repack conv/deconv weights to [ci][9][cout] (cout padded, zero-filled).
// conv  src: (coutR, cin, 3, 3);  deconv src: (cin, coutR, 3, 3).
__global__ void repack_k(const float* __restrict__ src, float* __restrict__ dst,
                         int cout, int coutR, int cin, int flip, int deconv)
{
    int t = blockIdx.x * 256 + threadIdx.x;
    int tot = cin * 9 * cout;
    if (t >= tot) return;
    int co = t % cout; int k = (t / cout) % 9; int ci = t / (9 * cout);
    float v = 0.f;
    if (co < coutR) {
        int ks = flip ? 8 - k : k;
        v = deconv ? src[((size_t)ci * coutR + co) * 9 + ks]
                   : src[((size_t)co * cin + ci) * 9 + ks];
    }
    dst[t] = v;
}

// ============ 3x3 conv s1 p1 — tile 32x32, thread = 2x2 out x 32 co =========
template<int CIN, bool RELU, bool ADDSELF>
__launch_bounds__(256, 2)
__global__ void conv3s1_k(const float* __restrict__ in, const float* __restrict__ wp,
                          const float* __restrict__ bias, float* __restrict__ out,
                          const float* __restrict__ addend, int COUT, int H, int W)
{
    constexpr int CB = 4;
    constexpr int PL = 34 * 34;               // 1156
    constexpr int NL = (CB * PL + 255) / 256; // 19
    constexpr int WT = CB * 9 * 32;           // 1152
    constexpr int NW = (WT + 255) / 256;      // 5
    __shared__ float smIn[CB * PL];
    __shared__ float smW[WT];

    const int tid = threadIdx.x;
    int b = blockIdx.x;
    const int chunks = COUT / 32;
    const int tX = W / 32, tY = H / 32;
    const int ch = b % chunks; b /= chunks;
    const int tx = b % tX; b /= tX;
    const int ty = b % tY; const int n = b / tY;
    const int cobase = ch * 32;
    const int r = tid >> 4, c = tid & 15;
    const int gy0 = ty * 32 - 1, gx0 = tx * 32 - 1;

    v4f acc[32];                               // [dy*2+dx][g]
#pragma unroll
    for (int g = 0; g < 8; ++g) {
        v4f bv = *(const v4f*)&bias[cobase + 4 * g];
#pragma unroll
        for (int pt = 0; pt < 4; ++pt) acc[pt * 8 + g] = bv;
    }

    const size_t plane = (size_t)H * W;
    const float* ip0 = in + (size_t)n * CIN * plane;
    const float* wp0 = wp + cobase;

    float gIn[NL], gW[NW];
    auto pre = [&](int ci0) {
#pragma unroll
        for (int l = 0; l < NL; ++l) {
            int idx = tid + 256 * l;
            float v = 0.f;
            if (idx < CB * PL) {
                int ci = idx / PL, rem = idx - ci * PL;
                int rr = rem / 34, cc = rem - rr * 34;
                int gy = gy0 + rr, gx = gx0 + cc;
                if (gy >= 0 && gy < H && gx >= 0 && gx < W)
                    v = ip0[(size_t)(ci0 + ci) * plane + (size_t)gy * W + gx];
            }
            gIn[l] = v;
        }
#pragma unroll
        for (int l = 0; l < NW; ++l) {
            int idx = tid + 256 * l;
            float v = 0.f;
            if (idx < WT) {
                int q2 = idx >> 5, co = idx & 31;
                v = wp0[((size_t)ci0 * 9 + q2) * COUT + co];
            }
            gW[l] = v;
        }
    };

    pre(0);
    for (int ci0 = 0; ci0 < CIN; ci0 += CB) {
        __syncthreads();
#pragma unroll
        for (int l = 0; l < NL; ++l) { int idx = tid + 256 * l; if (idx < CB * PL) smIn[idx] = gIn[l]; }
#pragma unroll
        for (int l = 0; l < NW; ++l) { int idx = tid + 256 * l; if (idx < WT) smW[idx] = gW[l]; }
        __syncthreads();
        if (ci0 + CB < CIN) pre(ci0 + CB);

#pragma unroll 1
        for (int ci = 0; ci < CB; ++ci) {
            float p[16];
            const float* sp = &smIn[ci * PL + (2 * r) * 34 + 2 * c];
#pragma unroll
            for (int i = 0; i < 4; ++i)
#pragma unroll
                for (int j = 0; j < 4; ++j)
                    p[i * 4 + j] = sp[i * 34 + j];
            const float* wrow = &smW[ci * 288];
#pragma unroll
            for (int k = 0; k < 9; ++k) {
                const int ky = k / 3, kx = k % 3;
#pragma unroll
                for (int g = 0; g < 8; ++g) {
                    v4f wv = *(const v4f*)&wrow[k * 32 + 4 * g];
#pragma unroll
                    for (int dy = 0; dy < 2; ++dy)
#pragma unroll
                        for (int dx = 0; dx < 2; ++dx)
                            fma4(acc[(dy * 2 + dx) * 8 + g], p[(dy + ky) * 4 + dx + kx], wv);
                }
            }
        }
    }

    const int oy0 = ty * 32 + 2 * r, ox0 = tx * 32 + 2 * c;
    float* op = out + ((size_t)n * COUT + cobase) * plane + (size_t)oy0 * W + ox0;
    const float* ap = ADDSELF ? addend + ((size_t)n * COUT + cobase) * plane + (size_t)oy0 * W + ox0
                              : nullptr;
#pragma unroll
    for (int g = 0; g < 8; ++g)
#pragma unroll
        for (int e = 0; e < 4; ++e) {
            size_t cOff = (size_t)(4 * g + e) * plane;
#pragma unroll
            for (int dy = 0; dy < 2; ++dy) {
                float v0 = acc[(dy * 2 + 0) * 8 + g][e];
                float v1 = acc[(dy * 2 + 1) * 8 + g][e];
                size_t o = cOff + (size_t)dy * W;
                if (ADDSELF) { float2 adn = *(const float2*)&ap[o]; v0 += adn.x; v1 += adn.y; }
                if (RELU) { v0 = fmaxf(v0, 0.f); v1 = fmaxf(v1, 0.f); }
                *(float2*)&op[o] = make_float2(v0, v1);
            }
        }
}

// ============ 3x3 conv s2 p1 — tile 32x32 out, thread = 2x2 out x 32 co =====
template<int CIN, bool RELU>
__launch_bounds__(256, 2)
__global__ void conv3s2_k(const float* __restrict__ in, const float* __restrict__ wp,
                          const float* __restrict__ bias, float* __restrict__ out,
                          int COUT, int Hin, int Win)
{
    constexpr int PL = 65 * 66;               // 4290
    constexpr int NL = (PL + 255) / 256;      // 17
    constexpr int WT = 9 * 32;                // 288
    constexpr int NW = 2;
    __shared__ float smIn[PL];
    __shared__ float smW[WT];

    const int Hout = Hin >> 1, Wout = Win >> 1;
    const int tid = threadIdx.x;
    int b = blockIdx.x;
    const int chunks = COUT / 32;
    const int tX = Wout / 32, tY = Hout / 32;
    const int ch = b % chunks; b /= chunks;
    const int tx = b % tX; b /= tX;
    const int ty = b % tY; const int n = b / tY;
    const int cobase = ch * 32;
    const int r = tid >> 4, c = tid & 15;
    const int gy0 = ty * 64 - 1, gx0 = tx * 64 - 1;

    v4f acc[32];
#pragma unroll
    for (int g = 0; g < 8; ++g) {
        v4f bv = *(const v4f*)&bias[cobase + 4 * g];
#pragma unroll
        for (int pt = 0; pt < 4; ++pt) acc[pt * 8 + g] = bv;
    }

    const size_t plane = (size_t)Hin * Win;
    const float* ip0 = in + (size_t)n * CIN * plane;
    const float* wp0 = wp + cobase;

    float gIn[NL], gW[NW];
    auto pre = [&](int ci0) {
#pragma unroll
        for (int l = 0; l < NL; ++l) {
            int idx = tid + 256 * l;
            float v = 0.f;
            if (idx < PL) {
                int rr = idx / 66, cc = idx - rr * 66;
                int gy = gy0 + rr, gx = gx0 + cc;
                if (gy >= 0 && gy < Hin && gx >= 0 && gx < Win)
                    v = ip0[(size_t)ci0 * plane + (size_t)gy * Win + gx];
            }
            gIn[l] = v;
        }
#pragma unroll
        for (int l = 0; l < NW; ++l) {
            int idx = tid + 256 * l;
            float v = 0.f;
            if (idx < WT) {
                int q2 = idx >> 5, co = idx & 31;
                v = wp0[((size_t)ci0 * 9 + q2) * COUT + co];
            }
            gW[l] = v;
        }
    };

    pre(0);
    for (int ci0 = 0; ci0 < CIN; ++ci0) {
        __syncthreads();
#pragma unroll
        for (int l = 0; l < NL; ++l) { int idx = tid + 256 * l; if (idx < PL) smIn[idx] = gIn[l]; }
#pragma unroll
        for (int l = 0; l < NW; ++l) { int idx = tid + 256 * l; if (idx < WT) smW[idx] = gW[l]; }
        __syncthreads();
        if (ci0 + 1 < CIN) pre(ci0 + 1);

        float p[25];
        const float* sp = &smIn[(4 * r) * 66 + 4 * c];
#pragma unroll
        for (int i = 0; i < 5; ++i)
#pragma unroll
            for (int j = 0; j < 5; ++j)
                p[i * 5 + j] = sp[i * 66 + j];
#pragma unroll
        for (int k = 0; k < 9; ++k) {
            const int ky = k / 3, kx = k % 3;
#pragma unroll
            for (int g = 0; g < 8; ++g) {
                v4f wv = *(const v4f*)&smW[k * 32 + 4 * g];
#pragma unroll
                for (int dy = 0; dy < 2; ++dy)
#pragma unroll
                    for (int dx = 0; dx < 2; ++dx)
                        fma4(acc[(dy * 2 + dx) * 8 + g], p[(2 * dy + ky) * 5 + 2 * dx + kx], wv);
            }
        }
    }

    const size_t outPlane = (size_t)Hout * Wout;
    const int oy0 = ty * 32 + 2 * r, ox0 = tx * 32 + 2 * c;
    float* op = out + ((size_t)n * COUT + cobase) * outPlane + (size_t)oy0 * Wout + ox0;
#pragma unroll
    for (int g = 0; g < 8; ++g)
#pragma unroll
        for (int e = 0; e < 4; ++e) {
            size_t cOff = (size_t)(4 * g + e) * outPlane;
#pragma unroll
            for (int dy = 0; dy < 2; ++dy) {
                float v0 = acc[(dy * 2 + 0) * 8 + g][e];
                float v1 = acc[(dy * 2 + 1) * 8 + g][e];
                if (RELU) { v0 = fmaxf(v0, 0.f); v1 = fmaxf(v1, 0.f); }
                *(float2*)&op[cOff + (size_t)dy * Wout] = make_float2(v0, v1);
            }
        }
}

// ====== 3x3 conv s1 p1 "b" variant — tile 16x32, 1x2 out x 32 co (small grids)
template<int CIN, bool RELU, bool ADDSELF>
__launch_bounds__(256, 4)
__global__ void conv3s1b_k(const float* __restrict__ in, const float* __restrict__ wp,
                           const float* __restrict__ bias, float* __restrict__ out,
                           const float* __restrict__ addend, int COUT, int H, int W)
{
    constexpr int CB = 4;
    constexpr int PL = 18 * 34;               // 612
    constexpr int NL = (CB * PL + 255) / 256; // 10
    constexpr int WT = CB * 9 * 32;           // 1152
    constexpr int NW = 5;
    __shared__ float smIn[CB * PL];
    __shared__ float smW[WT];

    const int tid = threadIdx.x;
    int b = blockIdx.x;
    const int chunks = COUT / 32;
    const int tX = W / 32, tY = H / 16;
    const int ch = b % chunks; b /= chunks;
    const int tx = b % tX; b /= tX;
    const int ty = b % tY; const int n = b / tY;
    const int cobase = ch * 32;
    const int r = tid >> 4, c = tid & 15;
    const int gy0 = ty * 16 - 1, gx0 = tx * 32 - 1;

    v4f acc[16];
#pragma unroll
    for (int g = 0; g < 8; ++g) {
        v4f bv = *(const v4f*)&bias[cobase + 4 * g];
        acc[g] = bv; acc[8 + g] = bv;
    }

    const size_t plane = (size_t)H * W;
    const float* ip0 = in + (size_t)n * CIN * plane;
    const float* wp0 = wp + cobase;

    float gIn[NL], gW[NW];
    auto pre = [&](int ci0) {
#pragma unroll
        for (int l = 0; l < NL; ++l) {
            int idx = tid + 256 * l;
            float v = 0.f;
            if (idx < CB * PL) {
                int ci = idx / PL, rem = idx - ci * PL;
                int rr = rem / 34, cc = rem - rr * 34;
                int gy = gy0 + rr, gx = gx0 + cc;
                if (gy >= 0 && gy < H && gx >= 0 && gx < W)
                    v = ip0[(size_t)(ci0 + ci) * plane + (size_t)gy * W + gx];
            }
            gIn[l] = v;
        }
#pragma unroll
        for (int l = 0; l < NW; ++l) {
            int idx = tid + 256 * l;
            float v = 0.f;
            if (idx < WT) {
                int q2 = idx >> 5, co = idx & 31;
                v = wp0[((size_t)ci0 * 9 + q2) * COUT + co];
            }
            gW[l] = v;
        }
    };

    pre(0);
    for (int ci0 = 0; ci0 < CIN; ci0 += CB) {
        __syncthreads();
#pragma unroll
        for (int l = 0; l < NL; ++l) { int idx = tid + 256 * l; if (idx < CB * PL) smIn[idx] = gIn[l]; }
#pragma unroll
        for (int l = 0; l < NW; ++l) { int idx = tid + 256 * l; if (idx < WT) smW[idx] = gW[l]; }
        __syncthreads();
        if (ci0 + CB < CIN) pre(ci0 + CB);

#pragma unroll 1
        for (int ci = 0; ci < CB; ++ci) {
            float p[12];
            const float* sp = &smIn[ci * PL + r * 34 + 2 * c];
#pragma unroll
            for (int i = 0; i < 3; ++i)
#pragma unroll
                for (int j = 0; j < 4; ++j)
                    p[i * 4 + j] = sp[i * 34 + j];
            const float* wrow = &smW[ci * 288];
#pragma unroll
            for (int k = 0; k < 9; ++k) {
                const int ky = k / 3, kx = k % 3;
#pragma unroll
                for (int g = 0; g < 8; ++g) {
                    v4f wv = *(const v4f*)&wrow[k * 32 + 4 * g];
                    fma4(acc[g],     p[ky * 4 + kx],     wv);
                    fma4(acc[8 + g], p[ky * 4 + kx + 1], wv);
                }
            }
        }
    }

    const int oy = ty * 16 + r, ox = tx * 32 + 2 * c;
    float* op = out + ((size_t)n * COUT + cobase) * plane + (size_t)oy * W + ox;
    const float* ap = ADDSELF ? addend + ((size_t)n * COUT + cobase) * plane + (size_t)oy * W + ox
                              : nullptr;
#pragma unroll
    for (int g = 0; g < 8; ++g)
#pragma unroll
        for (int e = 0; e < 4; ++e) {
            float v0 = acc[g][e], v1 = acc[8 + g][e];
            size_t o = (size_t)(4 * g + e) * plane;
            if (ADDSELF) { float2 adn = *(const float2*)&ap[o]; v0 += adn.x; v1 += adn.y; }
            if (RELU) { v0 = fmaxf(v0, 0.f); v1 = fmaxf(v1, 0.f); }
            *(float2*)&op[o] = make_float2(v0, v1);
        }
}

// =========== ConvTranspose k3 s2 p1 op1 — 2 quads/thread x COC co ===========
template<int CIN, int COC, bool RELU>
__launch_bounds__(256, 2)
__global__ void deconv2_k(const float* __restrict__ in, const float* __restrict__ wp,
                          const float* __restrict__ bias, float* __restrict__ out,
                          int COUTR, int COUTP, int Hin, int Win)
{
    constexpr int CB = 4;
    constexpr int RW = 33, RH = 17;
    constexpr int PL = RH * RW;               // 561
    constexpr int NL = (CB * PL + 255) / 256; // 9
    constexpr int WT = CB * 9 * COC;
    constexpr int NW = (WT + 255) / 256;
    __shared__ float smIn[CB * PL];
    __shared__ float smW[WT];

    const int Wout = Win * 2;
    const int tid = threadIdx.x;
    int b = blockIdx.x;
    const int chunks = COUTP / COC;
    const int qTX = Win / 32, qTY = Hin / 16;
    const int ch = b % chunks; b /= chunks;
    const int qtx = b % qTX; b /= qTX;
    const int qty = b % qTY; const int n = b / qTY;
    const int cobase = ch * COC;
    const int tqy = tid >> 4, tqx = tid & 15;
    const int qby = qty * 16, qbx = qtx * 32;

    v4f acc[8 * COC / 4];
#pragma unroll
    for (int g = 0; g < COC / 4; ++g) {
        v4f bv;
#pragma unroll
        for (int e = 0; e < 4; ++e)
            bv[e] = (cobase + 4 * g + e < COUTR) ? bias[cobase + 4 * g + e] : 0.f;
#pragma unroll
        for (int pt = 0; pt < 8; ++pt) acc[pt * (COC / 4) + g] = bv;
    }

    const size_t plane = (size_t)Hin * Win;
    const float* ip0 = in + (size_t)n * CIN * plane;
    const float* wp0 = wp + cobase;

    float gIn[NL], gW[NW];
    auto pre = [&](int ci0) {
#pragma unroll
        for (int l = 0; l < NL; ++l) {
            int idx = tid + 256 * l;
            float v = 0.f;
            if (idx < CB * PL) {
                int ci = idx / PL, rem = idx - ci * PL;
                int rr = rem / RW, cc = rem - rr * RW;
                int gy = qby + rr, gx = qbx + cc;
                if (gy < Hin && gx < Win)
                    v = ip0[(size_t)(ci0 + ci) * plane + (size_t)gy * Win + gx];
            }
            gIn[l] = v;
        }
#pragma unroll
        for (int l = 0; l < NW; ++l) {
            int idx = tid + 256 * l;
            float v = 0.f;
            if (idx < WT) {
                int q2 = idx / COC, co = idx % COC;
                v = wp0[((size_t)ci0 * 9 + q2) * COUTP + co];
            }
            gW[l] = v;
        }
    };

    pre(0);
    for (int ci0 = 0; ci0 < CIN; ci0 += CB) {
        __syncthreads();
#pragma unroll
        for (int l = 0; l < NL; ++l) { int idx = tid + 256 * l; if (idx < CB * PL) smIn[idx] = gIn[l]; }
#pragma unroll
        for (int l = 0; l < NW; ++l) { int idx = tid + 256 * l; if (idx < WT) smW[idx] = gW[l]; }
        __syncthreads();
        if (ci0 + CB < CIN) pre(ci0 + CB);

#pragma unroll 1
        for (int ci = 0; ci < CB; ++ci) {
            float p[6];
            const float* sp = &smIn[ci * PL + tqy * RW + 2 * tqx];
#pragma unroll
            for (int i = 0; i < 2; ++i)
#pragma unroll
                for (int j = 0; j < 3; ++j)
                    p[i * 3 + j] = sp[i * RW + j];
            const float* wrow = &smW[ci * 9 * COC];
#pragma unroll
            for (int k = 0; k < 9; ++k) {
                const int ky = k / 3, kx = k % 3;
                const int dy = (ky == 1) ? 0 : 1, iy = (ky == 0) ? 1 : 0;
                const int dx = (kx == 1) ? 0 : 1, ix = (kx == 0) ? 1 : 0;
#pragma unroll
                for (int g = 0; g < COC / 4; ++g) {
                    v4f wv = *(const v4f*)&wrow[k * COC + 4 * g];
                    fma4(acc[(0 + dy * 2 + dx) * (COC / 4) + g], p[iy * 3 + ix],     wv);
                    fma4(acc[(4 + dy * 2 + dx) * (COC / 4) + g], p[iy * 3 + ix + 1], wv);
                }
            }
        }
    }

    const size_t oPlane = (size_t)(Hin * 2) * Wout;
    const int oy = 2 * (qby + tqy), ox = 2 * (qbx + 2 * tqx);
#pragma unroll
    for (int g = 0; g < COC / 4; ++g)
#pragma unroll
        for (int e = 0; e < 4; ++e) {
            int cch = cobase + 4 * g + e;
            if (cch >= COUTR) break;
            float* op = out + ((size_t)n * COUTR + cch) * oPlane + (size_t)oy * Wout + ox;
#pragma unroll
            for (int a2 = 0; a2 < 2; ++a2) {
                float u0 = acc[(0 + a2 * 2 + 0) * (COC / 4) + g][e];
                float u1 = acc[(0 + a2 * 2 + 1) * (COC / 4) + g][e];
                float u2 = acc[(4 + a2 * 2 + 0) * (COC / 4) + g][e];
                float u3 = acc[(4 + a2 * 2 + 1) * (COC / 4) + g][e];
                if (RELU) { u0 = fmaxf(u0, 0.f); u1 = fmaxf(u1, 0.f);
                            u2 = fmaxf(u2, 0.f); u3 = fmaxf(u3, 0.f); }
                *(float4*)&op[(size_t)a2 * Wout] = make_float4(u0, u1, u2, u3);
            }
        }
}

// ===================== 1x1 conv stride S — 1 pos/thread, 32 co ==============
template<int CIN, int S, bool RELU>
__launch_bounds__(256, 4)
__global__ void conv1x1_k(const float* __restrict__ in, const float* __restrict__ w,
                          const float* __restrict__ bias, float* __restrict__ out,
                          int COUT, int Hin, int Win, int Hout, int Wout)
{
    constexpr int COC = 32;
    __shared__ float smW[CIN * COC];
    const int tid = threadIdx.x;
    int b = blockIdx.x;
    const int chunks = COUT / COC;
    const int spB = (Hout * Wout) / 256;
    const int ch = b % chunks; b /= chunks;
    const int sb = b % spB; const int n = b / spB;
    const int cobase = ch * COC;

    for (int idx = tid; idx < CIN * COC; idx += 256) {
        int ci = idx / COC, co = idx - ci * COC;
        smW[idx] = w[(size_t)(cobase + co) * CIN + ci];
    }
    __syncthreads();

    const int pos = sb * 256 + tid;
    const int oy = pos / Wout, ox = pos - oy * Wout;

    v4f acc[8];
#pragma unroll
    for (int g = 0; g < 8; ++g) acc[g] = *(const v4f*)&bias[cobase + 4 * g];

    const size_t inPlane = (size_t)Hin * Win;
    const float* ip = in + (size_t)n * CIN * inPlane + (size_t)(oy * S) * Win + (size_t)(ox * S);
#pragma unroll 1
    for (int ci = 0; ci < CIN; ++ci) {
        float v = ip[(size_t)ci * inPlane];
#pragma unroll
        for (int g = 0; g < 8; ++g)
            fma4(acc[g], v, *(const v4f*)&smW[ci * COC + 4 * g]);
    }
    const size_t outPlane = (size_t)Hout * Wout;
    float* op = out + ((size_t)n * COUT + cobase) * outPlane + pos;
#pragma unroll
    for (int g = 0; g < 8; ++g)
#pragma unroll
        for (int e = 0; e < 4; ++e) {
            float v = acc[g][e];
            if (RELU) v = fmaxf(v, 0.f);
            op[(size_t)(4 * g + e) * outPlane] = v;
        }
}

// ================== quantize — 2 positions/thread, float4 reads =============
__device__ __forceinline__ void dot4(v4f& d, v4f e, v4f cv) {
    d.x = fmaf(e.x, cv.x, d.x); d.y = fmaf(e.y, cv.y, d.y);
    d.z = fmaf(e.z, cv.z, d.z); d.w = fmaf(e.w, cv.w, d.w);
}

__launch_bounds__(256, 2)
__global__ void quantize_k(const float* __restrict__ h, const float* __restrict__ cb,
                           float* __restrict__ q)
{
    __shared__ float cn[512];
    __shared__ float cbl[128 * 64];
    const int tid = threadIdx.x;

    for (int i = tid; i < 512; i += 256) {
        v4f s = {0.f, 0.f, 0.f, 0.f};
#pragma unroll
        for (int j4 = 0; j4 < 16; ++j4) {
            v4f v = *(const v4f*)&cb[i * 64 + 4 * j4];
            dot4(s, v, v);
        }
        cn[i] = s.x + s.y + s.z + s.w;
    }

    const int t0 = blockIdx.x * 512 + tid;
    const int t1 = t0 + 256;
    const int n0 = t0 >> 12, r0 = t0 & 4095;
    const int n1 = t1 >> 12, r1 = t1 & 4095;
    const float* hp0 = h + (size_t)n0 * 64 * 4096 + r0;
    const float* hp1 = h + (size_t)n1 * 64 * 4096 + r1;
    v4f e0[16], e1[16];
#pragma unroll
    for (int j4 = 0; j4 < 16; ++j4)
#pragma unroll
        for (int e = 0; e < 4; ++e) {
            e0[j4][e] = hp0[(size_t)(4 * j4 + e) * 4096];
            e1[j4][e] = hp1[(size_t)(4 * j4 + e) * 4096];
        }

    float best0 = 3.4e38f, best1 = 3.4e38f; int bi0 = 0, bi1 = 0;
    for (int chn = 0; chn < 4; ++chn) {
        __syncthreads();
        const float4* src = reinterpret_cast<const float4*>(cb + chn * 128 * 64);
        float4* dst = reinterpret_cast<float4*>(cbl);
        for (int i = tid; i < 2048; i += 256) dst[i] = src[i];
        __syncthreads();
#pragma unroll 1
        for (int c = 0; c < 128; ++c) {
            v4f d0 = {0.f, 0.f, 0.f, 0.f}, d1 = {0.f, 0.f, 0.f, 0.f};
#pragma unroll
            for (int j4 = 0; j4 < 16; ++j4) {
                v4f cv = *(const v4f*)&cbl[c * 64 + 4 * j4];
                dot4(d0, e0[j4], cv);
                dot4(d1, e1[j4], cv);
            }
            float dist0 = cn[chn * 128 + c] - 2.f * (d0.x + d0.y + d0.z + d0.w);
            float dist1 = cn[chn * 128 + c] - 2.f * (d1.x + d1.y + d1.z + d1.w);
            if (dist0 < best0) { best0 = dist0; bi0 = chn * 128 + c; }
            if (dist1 < best1) { best1 = dist1; bi1 = chn * 128 + c; }
        }
    }

    const float* cr0 = cb + (size_t)bi0 * 64;
    const float* cr1 = cb + (size_t)bi1 * 64;
    float* qp0 = q + (size_t)n0 * 64 * 4096 + r0;
    float* qp1 = q + (size_t)n1 * 64 * 4096 + r1;
#pragma unroll
    for (int j4 = 0; j4 < 16; ++j4) {
        v4f a = *(const v4f*)&cr0[4 * j4];
        v4f b2 = *(const v4f*)&cr1[4 * j4];
#pragma unroll
        for (int e = 0; e < 4; ++e) {
            qp0[(size_t)(4 * j4 + e) * 4096] = a[e];
            qp1[(size_t)(4 * j4 + e) * 4096] = b2[e];
        }
    }
}

extern "C" void kernel_launch(void* const* d_in, const int* in_sizes, int n_in,
                              void* d_out, int out_size, void* d_ws, size_t ws_size,
                              hipStream_t stream)
{
    const float* x    = (const float*)d_in[0];
    const float* e0w1 = (const float*)d_in[1];  const float* e0b1 = (const float*)d_in[2];
    const float* e0w2 = (const float*)d_in[3];  const float* e0b2 = (const float*)d_in[4];
    const float* e0wd = (const float*)d_in[5];  const float* e0bd = (const float*)d_in[6];
    const float* e1w1 = (const float*)d_in[7];  const float* e1b1 = (const float*)d_in[8];
    const float* e1w2 = (const float*)d_in[9];  const float* e1b2 = (const float*)d_in[10];
    const float* e1wd = (const float*)d_in[11]; const float* e1bd = (const float*)d_in[12];
    const float* e2w1 = (const float*)d_in[13]; const float* e2b1 = (const float*)d_in[14];
    const float* e2w2 = (const float*)d_in[15]; const float* e2b2 = (const float*)d_in[16];
    const float* e2wd = (const float*)d_in[17]; const float* e2bd = (const float*)d_in[18];
    const float* d0w  = (const float*)d_in[19]; const float* d0b  = (const float*)d_in[20];
    const float* d1w  = (const float*)d_in[21]; const float* d1b  = (const float*)d_in[22];
    const float* d2w  = (const float*)d_in[23]; const float* d2b  = (const float*)d_in[24];
    const float* cb   = (const float*)d_in[25];
    float* out = (float*)d_out;
    float* ws  = (float*)d_ws;

    // packed weights in d_out's slack (overwritten only by the final dec2)
    float* P_e0w1 = out + 0;
    float* P_e0w2 = out + 1728;
    float* P_e1w1 = out + 38592;
    float* P_e1w2 = out + 112320;
    float* P_e2w1 = out + 259776;
    float* P_e2w2 = out + 333504;
    float* P_d0w  = out + 370368;
    float* P_d1w  = ws + 50331648;      // packed after S1 is dead
    float* P_d2w  = ws + 50405376;      // + 73728

    // ws activation layout (floats), liveness-planned, total 67,108,864 floats:
    float* S0 = ws;                     // [0, 33.5M)  enc0 out (32,64,128,128)
    float* T1 = ws + 33554432;          // [33.5M, 67.1M) enc0 conv1 out (full batch)
    float* T3 = ws + 33554432;          // [33.5M, 50.3M) enc1 conv1 out
    float* S1 = ws + 50331648;          // [50.3M, 67.1M) enc1 out (32,128,64,64)
    float* S2 = ws;                     // [0, 8.4M)   enc2 out
    float* T5 = ws + 8388608;           // [8.4M, 16.8M)
    float* Q  = ws + 16777216;          // [16.8M, 25.2M)
    float* D0 = ws + 33554432;          // [33.5M, 50.3M) dec0 out
    float* D1 = ws;                     // [0, 33.5M)  dec1 out

    dim3 blk(256);
    auto rp = [&](const float* src, float* dst, int cout, int coutR, int cin, int flip, int dec) {
        int tot = cin * 9 * cout;
        repack_k<<<dim3((tot + 255) / 256), blk, 0, stream>>>(src, dst, cout, coutR, cin, flip, dec);
    };

    rp(e0w1, P_e0w1, 64, 64, 3, 0, 0);
    rp(e0w2, P_e0w2, 64, 64, 64, 0, 0);
    rp(e1w1, P_e1w1, 128, 128, 64, 0, 0);
    rp(e1w2, P_e1w2, 128, 128, 128, 0, 0);
    rp(e2w1, P_e2w1, 64, 64, 128, 0, 0);
    rp(e2w2, P_e2w2, 64, 64, 64, 0, 0);
    rp(d0w,  P_d0w, 128, 128, 64, 1, 1);

    // --- enc0 (3 -> 64, s2): 256 -> 128, full batch ---
    conv1x1_k<3, 2, false><<<dim3(32 * 64 * 2), blk, 0, stream>>>(
        x, e0wd, e0bd, S0, 64, 256, 256, 128, 128);
    conv3s2_k<3, true><<<dim3(32 * 4 * 4 * 2), blk, 0, stream>>>(
        x, P_e0w1, e0b1, T1, 64, 256, 256);
    conv3s1_k<64, true, true><<<dim3(32 * 4 * 4 * 2), blk, 0, stream>>>(
        T1, P_e0w2, e0b2, S0, S0, 64, 128, 128);

    // --- enc1 (64 -> 128, s2): 128 -> 64 ---
    conv1x1_k<64, 2, false><<<dim3(32 * 16 * 4), blk, 0, stream>>>(
        S0, e1wd, e1bd, S1, 128, 128, 128, 64, 64);
    conv3s2_k<64, true><<<dim3(32 * 2 * 2 * 4), blk, 0, stream>>>(
        S0, P_e1w1, e1b1, T3, 128, 128, 128);
    conv3s1_k<128, true, true><<<dim3(32 * 2 * 2 * 4), blk, 0, stream>>>(
        T3, P_e1w2, e1b2, S1, S1, 128, 64, 64);

    // --- enc2 (128 -> 64, s1) ---
    conv1x1_k<128, 1, false><<<dim3(32 * 16 * 2), blk, 0, stream>>>(
        S1, e2wd, e2bd, S2, 64, 64, 64, 64, 64);
    conv3s1b_k<128, true, false><<<dim3(32 * 8 * 2), blk, 0, stream>>>(
        S1, P_e2w1, e2b1, T5, nullptr, 64, 64, 64);
    rp(d1w, P_d1w, 64, 64, 128, 0, 1);          // S1 dead after the two reads above
    rp(d2w, P_d2w, 4, 3, 64, 0, 1);
    conv3s1b_k<64, true, true><<<dim3(32 * 8 * 2), blk, 0, stream>>>(
        T5, P_e2w2, e2b2, S2, S2, 64, 64, 64);

    // --- quantize ---
    quantize_k<<<dim3(256), blk, 0, stream>>>(S2, cb, Q);

    // --- dec0: ConvT s1 (64 -> 128) as flipped conv, ReLU ---
    conv3s1_k<64, true, false><<<dim3(32 * 2 * 2 * 4), blk, 0, stream>>>(
        Q, P_d0w, d0b, D0, nullptr, 128, 64, 64);

    // --- dec1: ConvT s2 (128 -> 64), ReLU: 64 -> 128 ---
    deconv2_k<128, 16, true><<<dim3(32 * 2 * 4 * 4), blk, 0, stream>>>(
        D0, P_d1w, d1b, D1, 64, 64, 64, 64);

    // --- dec2: ConvT s2 (64 -> 3): 128 -> 256 ---
    deconv2_k<64, 4, false><<<dim3(32 * 4 * 8), blk, 0, stream>>>(
        D1, P_d2w, d2b, out, 3, 4, 128, 128);
}

// Round 5
// 3661.283 us; speedup vs baseline: 1.4496x; 1.4496x over previous
//
#include <hip/hip_runtime.h>
#include <cstddef>

// ---------------------------------------------------------------------------
// VQ-VAE forward, fp32 direct conv. Round 5: round-3 structure (no register
// prefetch — round-4's pipeline spilled to scratch: FETCH 296MB->1GB), with
// conv3s1 retiled to 2x2 outputs x 16 co per thread (same 64 acc floats,
// each weight ds_read_b128 feeds 4 fma4 instead of 2).
// ---------------------------------------------------------------------------

typedef float v4f __attribute__((ext_vector_type(4)));

__device__ __forceinline__ void fma4(v4f& a, float p, const v4f& w) {
    a.x = fmaf(p, w.x, a.x); a.y = fmaf(p, w.y, a.y);
    a.z = fmaf(p, w.z, a.z); a.w = fmaf(p, w.w, a.w);
}

// Repack conv/deconv weights to [ci][9][cout] (cout padded, zero-filled).
// conv  src: (coutR, cin, 3, 3);  deconv src: (cin, coutR, 3, 3).
__global__ void repack_k(const float* __restrict__ src, float* __restrict__ dst,
                         int cout, int coutR, int cin, int flip, int deconv)
{
    int t = blockIdx.x * 256 + threadIdx.x;
    int tot = cin * 9 * cout;
    if (t >= tot) return;
    int co = t % cout; int k = (t / cout) % 9; int ci = t / (9 * cout);
    float v = 0.f;
    if (co < coutR) {
        int ks = flip ? 8 - k : k;
        v = deconv ? src[((size_t)ci * coutR + co) * 9 + ks]
                   : src[((size_t)co * cin + ci) * 9 + ks];
    }
    dst[t] = v;
}

// ============ 3x3 conv s1 p1 — tile 32x32, thread = 2x2 out x 16 co =========
template<int CIN, bool RELU, bool ADDSELF>
__launch_bounds__(256, 4)
__global__ void conv3s1_k(const float* __restrict__ in, const float* __restrict__ wp,
                          const float* __restrict__ bias, float* __restrict__ out,
                          const float* __restrict__ addend, int COUT, int H, int W)
{
    constexpr int CB = 4;
    constexpr int PL = 34 * 34;                 // 1156
    __shared__ float smIn[CB * PL];
    __shared__ float smW[CB * 144];             // [ci][9][16]

    const int tid = threadIdx.x;
    int b = blockIdx.x;
    const int chunks = COUT / 16;
    const int tX = W / 32, tY = H / 32;
    const int ch = b % chunks; b /= chunks;
    const int tx = b % tX; b /= tX;
    const int ty = b % tY; const int n = b / tY;
    const int cobase = ch * 16;
    const int r = tid >> 4, c = tid & 15;
    const int gy0 = ty * 32 - 1, gx0 = tx * 32 - 1;

    v4f acc[16];                                // [dy*2+dx][g], g<4
#pragma unroll
    for (int g = 0; g < 4; ++g) {
        v4f bv = *(const v4f*)&bias[cobase + 4 * g];
#pragma unroll
        for (int pt = 0; pt < 4; ++pt) acc[pt * 4 + g] = bv;
    }

    const size_t plane = (size_t)H * W;
    const float* ip0 = in + (size_t)n * CIN * plane;
    const float* wp0 = wp + cobase;

    for (int ci0 = 0; ci0 < CIN; ci0 += CB) {
        __syncthreads();
        for (int idx = tid; idx < CB * PL; idx += 256) {
            int ci = idx / PL, rem = idx - ci * PL;
            int rr = rem / 34, cc = rem - rr * 34;
            int gy = gy0 + rr, gx = gx0 + cc;
            float v = 0.f;
            if (gy >= 0 && gy < H && gx >= 0 && gx < W)
                v = ip0[(size_t)(ci0 + ci) * plane + (size_t)gy * W + gx];
            smIn[idx] = v;
        }
        for (int idx = tid; idx < CB * 144; idx += 256) {
            int q2 = idx >> 4, co = idx & 15;   // q2 = ci*9 + k
            smW[idx] = wp0[((size_t)ci0 * 9 + q2) * COUT + co];
        }
        __syncthreads();

#pragma unroll 1
        for (int ci = 0; ci < CB; ++ci) {
            float p[16];
            const float* sp = &smIn[ci * PL + (2 * r) * 34 + 2 * c];
#pragma unroll
            for (int i = 0; i < 4; ++i)
#pragma unroll
                for (int j = 0; j < 4; ++j)
                    p[i * 4 + j] = sp[i * 34 + j];
            const float* wrow = &smW[ci * 144];
#pragma unroll
            for (int k = 0; k < 9; ++k) {
                const int ky = k / 3, kx = k % 3;
#pragma unroll
                for (int g = 0; g < 4; ++g) {
                    v4f wv = *(const v4f*)&wrow[k * 16 + 4 * g];
#pragma unroll
                    for (int dy = 0; dy < 2; ++dy)
#pragma unroll
                        for (int dx = 0; dx < 2; ++dx)
                            fma4(acc[(dy * 2 + dx) * 4 + g], p[(dy + ky) * 4 + dx + kx], wv);
                }
            }
        }
    }

    const int oy0 = ty * 32 + 2 * r, ox0 = tx * 32 + 2 * c;
    float* op = out + ((size_t)n * COUT + cobase) * plane + (size_t)oy0 * W + ox0;
    const float* ap = ADDSELF ? addend + ((size_t)n * COUT + cobase) * plane + (size_t)oy0 * W + ox0
                              : nullptr;
#pragma unroll
    for (int g = 0; g < 4; ++g)
#pragma unroll
        for (int e = 0; e < 4; ++e) {
            size_t cOff = (size_t)(4 * g + e) * plane;
#pragma unroll
            for (int dy = 0; dy < 2; ++dy) {
                float v0 = acc[(dy * 2 + 0) * 4 + g][e];
                float v1 = acc[(dy * 2 + 1) * 4 + g][e];
                size_t o = cOff + (size_t)dy * W;
                if (ADDSELF) { float2 adn = *(const float2*)&ap[o]; v0 += adn.x; v1 += adn.y; }
                if (RELU) { v0 = fmaxf(v0, 0.f); v1 = fmaxf(v1, 0.f); }
                *(float2*)&op[o] = make_float2(v0, v1);
            }
        }
}

// ===================== 3x3 conv s2 p1 — tile 16x32 out, 1x2 out x 32 co =====
template<int CIN, int CB, bool RELU>
__launch_bounds__(256, 4)
__global__ void conv3s2_k(const float* __restrict__ in, const float* __restrict__ wp,
                          const float* __restrict__ bias, float* __restrict__ out,
                          int COUT, int Hin, int Win)
{
    constexpr int COC = 32;
    __shared__ float smIn[CB * 2178];           // 33 x 66
    __shared__ float smW[CB * 9 * COC];
    const int Hout = Hin >> 1, Wout = Win >> 1;
    const int tid = threadIdx.x;
    int b = blockIdx.x;
    const int chunks = COUT / COC;
    const int tX = Wout / 32, tY = Hout / 16;
    const int ch = b % chunks; b /= chunks;
    const int tx = b % tX; b /= tX;
    const int ty = b % tY; const int n = b / tY;
    const int cobase = ch * COC;
    const int r = tid >> 4, c = tid & 15;
    const int gy0 = ty * 32 - 1, gx0 = tx * 64 - 1;

    v4f acc[16];
#pragma unroll
    for (int g = 0; g < 8; ++g) {
        v4f bv = *(const v4f*)&bias[cobase + 4 * g];
        acc[g] = bv; acc[8 + g] = bv;
    }

    const size_t plane = (size_t)Hin * Win;
    const float* ip0 = in + (size_t)n * CIN * plane;
    const float* wp0 = wp + cobase;

    for (int ci0 = 0; ci0 < CIN; ci0 += CB) {
        __syncthreads();
        for (int idx = tid; idx < CB * 2178; idx += 256) {
            int ci = idx / 2178, rem = idx - ci * 2178;
            int rr = rem / 66, cc = rem - rr * 66;
            int gy = gy0 + rr, gx = gx0 + cc;
            float v = 0.f;
            if (gy >= 0 && gy < Hin && gx >= 0 && gx < Win)
                v = ip0[(size_t)(ci0 + ci) * plane + (size_t)gy * Win + gx];
            smIn[idx] = v;
        }
        for (int idx = tid; idx < CB * 9 * COC; idx += 256) {
            int q2 = idx >> 5, co = idx & 31;
            smW[idx] = wp0[((size_t)ci0 * 9 + q2) * COUT + co];
        }
        __syncthreads();

#pragma unroll 1
        for (int ci = 0; ci < CB; ++ci) {
            float p[15];
            const float* sp = &smIn[ci * 2178 + 2 * r * 66 + 4 * c];
#pragma unroll
            for (int i = 0; i < 3; ++i)
#pragma unroll
                for (int j = 0; j < 5; ++j)
                    p[i * 5 + j] = sp[i * 66 + j];
            const float* wrow = &smW[ci * 288];
#pragma unroll
            for (int k = 0; k < 9; ++k) {
                const int ky = k / 3, kx = k % 3;
#pragma unroll
                for (int g = 0; g < 8; ++g) {
                    v4f wv = *(const v4f*)&wrow[k * 32 + 4 * g];
                    fma4(acc[g],     p[ky * 5 + kx],     wv);
                    fma4(acc[8 + g], p[ky * 5 + kx + 2], wv);
                }
            }
        }
    }

    const size_t outPlane = (size_t)Hout * Wout;
    const int oy = ty * 16 + r, ox = tx * 32 + 2 * c;
    float* op = out + ((size_t)n * COUT + cobase) * outPlane + (size_t)oy * Wout + ox;
#pragma unroll
    for (int g = 0; g < 8; ++g)
#pragma unroll
        for (int e = 0; e < 4; ++e) {
            float v0 = acc[g][e], v1 = acc[8 + g][e];
            if (RELU) { v0 = fmaxf(v0, 0.f); v1 = fmaxf(v1, 0.f); }
            *(float2*)&op[(size_t)(4 * g + e) * outPlane] = make_float2(v0, v1);
        }
}

// =========== ConvTranspose k3 s2 p1 op1 — 2 quads/thread x COC co ===========
template<int CIN, int CB, int COC, bool RELU>
__launch_bounds__(256, 3)
__global__ void deconv2_k(const float* __restrict__ in, const float* __restrict__ wp,
                          const float* __restrict__ bias, float* __restrict__ out,
                          int COUTR, int COUTP, int Hin, int Win)
{
    constexpr int RW = 33, RH = 17;
    __shared__ float smIn[CB * RH * RW];
    __shared__ float smW[CB * 9 * COC];
    const int Wout = Win * 2;
    const int tid = threadIdx.x;
    int b = blockIdx.x;
    const int chunks = COUTP / COC;
    const int qTX = Win / 32, qTY = Hin / 16;
    const int ch = b % chunks; b /= chunks;
    const int qtx = b % qTX; b /= qTX;
    const int qty = b % qTY; const int n = b / qTY;
    const int cobase = ch * COC;
    const int tqy = tid >> 4, tqx = tid & 15;
    const int qby = qty * 16, qbx = qtx * 32;

    v4f acc[8 * COC / 4];
#pragma unroll
    for (int g = 0; g < COC / 4; ++g) {
        v4f bv;
#pragma unroll
        for (int e = 0; e < 4; ++e)
            bv[e] = (cobase + 4 * g + e < COUTR) ? bias[cobase + 4 * g + e] : 0.f;
#pragma unroll
        for (int pt = 0; pt < 8; ++pt) acc[pt * (COC / 4) + g] = bv;
    }

    const size_t plane = (size_t)Hin * Win;
    const float* ip0 = in + (size_t)n * CIN * plane;
    const float* wp0 = wp + cobase;

    for (int ci0 = 0; ci0 < CIN; ci0 += CB) {
        __syncthreads();
        for (int idx = tid; idx < CB * RH * RW; idx += 256) {
            int ci = idx / (RH * RW), rem = idx - ci * (RH * RW);
            int rr = rem / RW, cc = rem - rr * RW;
            int gy = qby + rr, gx = qbx + cc;
            float v = 0.f;
            if (gy < Hin && gx < Win)
                v = ip0[(size_t)(ci0 + ci) * plane + (size_t)gy * Win + gx];
            smIn[idx] = v;
        }
        for (int idx = tid; idx < CB * 9 * COC; idx += 256) {
            int q2 = idx / COC, co = idx % COC;
            smW[idx] = wp0[((size_t)ci0 * 9 + q2) * COUTP + co];
        }
        __syncthreads();

#pragma unroll 1
        for (int ci = 0; ci < CB; ++ci) {
            float p[6];
            const float* sp = &smIn[ci * RH * RW + tqy * RW + 2 * tqx];
#pragma unroll
            for (int i = 0; i < 2; ++i)
#pragma unroll
                for (int j = 0; j < 3; ++j)
                    p[i * 3 + j] = sp[i * RW + j];
            const float* wrow = &smW[ci * 9 * COC];
#pragma unroll
            for (int k = 0; k < 9; ++k) {
                const int ky = k / 3, kx = k % 3;
                const int dy = (ky == 1) ? 0 : 1, iy = (ky == 0) ? 1 : 0;
                const int dx = (kx == 1) ? 0 : 1, ix = (kx == 0) ? 1 : 0;
#pragma unroll
                for (int g = 0; g < COC / 4; ++g) {
                    v4f wv = *(const v4f*)&wrow[k * COC + 4 * g];
                    fma4(acc[(0 + dy * 2 + dx) * (COC / 4) + g], p[iy * 3 + ix],     wv);
                    fma4(acc[(4 + dy * 2 + dx) * (COC / 4) + g], p[iy * 3 + ix + 1], wv);
                }
            }
        }
    }

    const size_t oPlane = (size_t)(Hin * 2) * Wout;
    const int oy = 2 * (qby + tqy), ox = 2 * (qbx + 2 * tqx);
#pragma unroll
    for (int g = 0; g < COC / 4; ++g)
#pragma unroll
        for (int e = 0; e < 4; ++e) {
            int cch = cobase + 4 * g + e;
            if (cch >= COUTR) break;
            float* op = out + ((size_t)n * COUTR + cch) * oPlane + (size_t)oy * Wout + ox;
#pragma unroll
            for (int a2 = 0; a2 < 2; ++a2) {
                float u0 = acc[(0 + a2 * 2 + 0) * (COC / 4) + g][e];
                float u1 = acc[(0 + a2 * 2 + 1) * (COC / 4) + g][e];
                float u2 = acc[(4 + a2 * 2 + 0) * (COC / 4) + g][e];
                float u3 = acc[(4 + a2 * 2 + 1) * (COC / 4) + g][e];
                if (RELU) { u0 = fmaxf(u0, 0.f); u1 = fmaxf(u1, 0.f);
                            u2 = fmaxf(u2, 0.f); u3 = fmaxf(u3, 0.f); }
                *(float4*)&op[(size_t)a2 * Wout] = make_float4(u0, u1, u2, u3);
            }
        }
}

// ===================== 1x1 conv stride S — 1 pos/thread, 32 co ==============
template<int CIN, int S, bool RELU>
__launch_bounds__(256, 4)
__global__ void conv1x1_k(const float* __restrict__ in, const float* __restrict__ w,
                          const float* __restrict__ bias, float* __restrict__ out,
                          int COUT, int Hin, int Win, int Hout, int Wout)
{
    constexpr int COC = 32;
    __shared__ float smW[CIN * COC];
    const int tid = threadIdx.x;
    int b = blockIdx.x;
    const int chunks = COUT / COC;
    const int spB = (Hout * Wout) / 256;
    const int ch = b % chunks; b /= chunks;
    const int sb = b % spB; const int n = b / spB;
    const int cobase = ch * COC;

    for (int idx = tid; idx < CIN * COC; idx += 256) {
        int ci = idx / COC, co = idx - ci * COC;
        smW[idx] = w[(size_t)(cobase + co) * CIN + ci];
    }
    __syncthreads();

    const int pos = sb * 256 + tid;
    const int oy = pos / Wout, ox = pos - oy * Wout;

    v4f acc[8];
#pragma unroll
    for (int g = 0; g < 8; ++g) acc[g] = *(const v4f*)&bias[cobase + 4 * g];

    const size_t inPlane = (size_t)Hin * Win;
    const float* ip = in + (size_t)n * CIN * inPlane + (size_t)(oy * S) * Win + (size_t)(ox * S);
#pragma unroll 1
    for (int ci = 0; ci < CIN; ++ci) {
        float v = ip[(size_t)ci * inPlane];
#pragma unroll
        for (int g = 0; g < 8; ++g)
            fma4(acc[g], v, *(const v4f*)&smW[ci * COC + 4 * g]);
    }
    const size_t outPlane = (size_t)Hout * Wout;
    float* op = out + ((size_t)n * COUT + cobase) * outPlane + pos;
#pragma unroll
    for (int g = 0; g < 8; ++g)
#pragma unroll
        for (int e = 0; e < 4; ++e) {
            float v = acc[g][e];
            if (RELU) v = fmaxf(v, 0.f);
            op[(size_t)(4 * g + e) * outPlane] = v;
        }
}

// ============================== quantize ===================================
__launch_bounds__(256)
__global__ void quantize_k(const float* __restrict__ h, const float* __restrict__ cb,
                           float* __restrict__ q)
{
    __shared__ float cn[512];
    __shared__ float cbl[128 * 64];
    const int tid = threadIdx.x;

    for (int i = tid; i < 512; i += 256) {
        float s = 0.f;
#pragma unroll
        for (int j = 0; j < 64; ++j) { float v = cb[i * 64 + j]; s = fmaf(v, v, s); }
        cn[i] = s;
    }

    const int t = blockIdx.x * 256 + tid;
    const int n = t >> 12, rem = t & 4095;
    const float* hp = h + (size_t)n * 64 * 4096 + rem;
    float e[64];
#pragma unroll
    for (int j = 0; j < 64; ++j) e[j] = hp[(size_t)j * 4096];

    float best = 3.4e38f; int bi = 0;
    for (int chn = 0; chn < 4; ++chn) {
        __syncthreads();
        const float4* src = reinterpret_cast<const float4*>(cb + chn * 128 * 64);
        float4* dst = reinterpret_cast<float4*>(cbl);
        for (int i = tid; i < 128 * 64 / 4; i += 256) dst[i] = src[i];
        __syncthreads();
        for (int c = 0; c < 128; ++c) {
            float dot = 0.f;
#pragma unroll
            for (int j = 0; j < 64; ++j) dot = fmaf(e[j], cbl[c * 64 + j], dot);
            float d = cn[chn * 128 + c] - 2.f * dot;
            if (d < best) { best = d; bi = chn * 128 + c; }
        }
    }

    const float* crow = cb + (size_t)bi * 64;
    float* qp = q + (size_t)n * 64 * 4096 + rem;
#pragma unroll
    for (int j = 0; j < 64; ++j) qp[(size_t)j * 4096] = crow[j];
}

extern "C" void kernel_launch(void* const* d_in, const int* in_sizes, int n_in,
                              void* d_out, int out_size, void* d_ws, size_t ws_size,
                              hipStream_t stream)
{
    const float* x    = (const float*)d_in[0];
    const float* e0w1 = (const float*)d_in[1];  const float* e0b1 = (const float*)d_in[2];
    const float* e0w2 = (const float*)d_in[3];  const float* e0b2 = (const float*)d_in[4];
    const float* e0wd = (const float*)d_in[5];  const float* e0bd = (const float*)d_in[6];
    const float* e1w1 = (const float*)d_in[7];  const float* e1b1 = (const float*)d_in[8];
    const float* e1w2 = (const float*)d_in[9];  const float* e1b2 = (const float*)d_in[10];
    const float* e1wd = (const float*)d_in[11]; const float* e1bd = (const float*)d_in[12];
    const float* e2w1 = (const float*)d_in[13]; const float* e2b1 = (const float*)d_in[14];
    const float* e2w2 = (const float*)d_in[15]; const float* e2b2 = (const float*)d_in[16];
    const float* e2wd = (const float*)d_in[17]; const float* e2bd = (const float*)d_in[18];
    const float* d0w  = (const float*)d_in[19]; const float* d0b  = (const float*)d_in[20];
    const float* d1w  = (const float*)d_in[21]; const float* d1b  = (const float*)d_in[22];
    const float* d2w  = (const float*)d_in[23]; const float* d2b  = (const float*)d_in[24];
    const float* cb   = (const float*)d_in[25];
    float* out = (float*)d_out;
    float* ws  = (float*)d_ws;

    // packed weights in d_out's slack (overwritten only by the final dec2)
    float* P_e0w1 = out + 0;
    float* P_e0w2 = out + 1728;
    float* P_e1w1 = out + 38592;
    float* P_e1w2 = out + 112320;
    float* P_e2w1 = out + 259776;
    float* P_e2w2 = out + 333504;
    float* P_d0w  = out + 370368;
    float* P_d1w  = ws + 50331648;      // packed after S1 is dead
    float* P_d2w  = ws + 50405376;      // + 73728

    // ws activation layout (floats), liveness-planned, total 67,108,864 floats:
    float* S0 = ws;                     // [0, 33.5M)  enc0 out (32,64,128,128)
    float* T1 = ws + 33554432;          // [33.5M, 67.1M) enc0 conv1 out (full batch)
    float* T3 = ws + 33554432;          // [33.5M, 50.3M) enc1 conv1 out
    float* S1 = ws + 50331648;          // [50.3M, 67.1M) enc1 out (32,128,64,64)
    float* S2 = ws;                     // [0, 8.4M)   enc2 out
    float* T5 = ws + 8388608;           // [8.4M, 16.8M)
    float* Q  = ws + 16777216;          // [16.8M, 25.2M)
    float* D0 = ws + 33554432;          // [33.5M, 50.3M) dec0 out
    float* D1 = ws;                     // [0, 33.5M)  dec1 out

    dim3 blk(256);
    auto rp = [&](const float* src, float* dst, int cout, int coutR, int cin, int flip, int dec) {
        int tot = cin * 9 * cout;
        repack_k<<<dim3((tot + 255) / 256), blk, 0, stream>>>(src, dst, cout, coutR, cin, flip, dec);
    };

    rp(e0w1, P_e0w1, 64, 64, 3, 0, 0);
    rp(e0w2, P_e0w2, 64, 64, 64, 0, 0);
    rp(e1w1, P_e1w1, 128, 128, 64, 0, 0);
    rp(e1w2, P_e1w2, 128, 128, 128, 0, 0);
    rp(e2w1, P_e2w1, 64, 64, 128, 0, 0);
    rp(e2w2, P_e2w2, 64, 64, 64, 0, 0);
    rp(d0w,  P_d0w, 128, 128, 64, 1, 1);

    // --- enc0 (3 -> 64, s2): 256 -> 128, full batch ---
    conv1x1_k<3, 2, false><<<dim3(32 * 64 * 2), blk, 0, stream>>>(
        x, e0wd, e0bd, S0, 64, 256, 256, 128, 128);
    conv3s2_k<3, 3, true><<<dim3(32 * 8 * 4 * 2), blk, 0, stream>>>(
        x, P_e0w1, e0b1, T1, 64, 256, 256);
    conv3s1_k<64, true, true><<<dim3(32 * 4 * 4 * 4), blk, 0, stream>>>(
        T1, P_e0w2, e0b2, S0, S0, 64, 128, 128);

    // --- enc1 (64 -> 128, s2): 128 -> 64 ---
    conv1x1_k<64, 2, false><<<dim3(32 * 16 * 4), blk, 0, stream>>>(
        S0, e1wd, e1bd, S1, 128, 128, 128, 64, 64);
    conv3s2_k<64, 4, true><<<dim3(32 * 4 * 2 * 4), blk, 0, stream>>>(
        S0, P_e1w1, e1b1, T3, 128, 128, 128);
    conv3s1_k<128, true, true><<<dim3(32 * 2 * 2 * 8), blk, 0, stream>>>(
        T3, P_e1w2, e1b2, S1, S1, 128, 64, 64);

    // --- enc2 (128 -> 64, s1) ---
    conv1x1_k<128, 1, false><<<dim3(32 * 16 * 2), blk, 0, stream>>>(
        S1, e2wd, e2bd, S2, 64, 64, 64, 64, 64);
    conv3s1_k<128, true, false><<<dim3(32 * 2 * 2 * 4), blk, 0, stream>>>(
        S1, P_e2w1, e2b1, T5, nullptr, 64, 64, 64);
    rp(d1w, P_d1w, 64, 64, 128, 0, 1);          // S1 dead after the two reads above
    rp(d2w, P_d2w, 4, 3, 64, 0, 1);
    conv3s1_k<64, true, true><<<dim3(32 * 2 * 2 * 4), blk, 0, stream>>>(
        T5, P_e2w2, e2b2, S2, S2, 64, 64, 64);

    // --- quantize ---
    quantize_k<<<dim3(512), blk, 0, stream>>>(S2, cb, Q);

    // --- dec0: ConvT s1 (64 -> 128) as flipped conv, ReLU ---
    conv3s1_k<64, true, false><<<dim3(32 * 2 * 2 * 8), blk, 0, stream>>>(
        Q, P_d0w, d0b, D0, nullptr, 128, 64, 64);

    // --- dec1: ConvT s2 (128 -> 64), ReLU: 64 -> 128 ---
    deconv2_k<128, 4, 16, true><<<dim3(32 * 2 * 4 * 4), blk, 0, stream>>>(
        D0, P_d1w, d1b, D1, 64, 64, 64, 64);

    // --- dec2: ConvT s2 (64 -> 3): 128 -> 256 ---
    deconv2_k<64, 8, 4, false><<<dim3(32 * 4 * 8), blk, 0, stream>>>(
        D1, P_d2w, d2b, out, 3, 4, 128, 128);
}

// Round 6
// 2440.273 us; speedup vs baseline: 2.1749x; 1.5004x over previous
//
#include <hip/hip_runtime.h>
#include <cstddef>

// ---------------------------------------------------------------------------
// VQ-VAE forward. Round 6: 3x3-s1 conv layers on MFMA (fp16 hi/lo split,
// 3 products, implicit GEMM, tap-major K, channels-last LDS A-tile).
// Stride-2 convs / deconvs / 1x1 / quantize keep the proven fp32 kernels.
// ---------------------------------------------------------------------------

typedef float v4f __attribute__((ext_vector_type(4)));
typedef _Float16 f16x8 __attribute__((ext_vector_type(8)));

__device__ __forceinline__ void fma4(v4f& a, float p, const v4f& w) {
    a.x = fmaf(p, w.x, a.x); a.y = fmaf(p, w.y, a.y);
    a.z = fmaf(p, w.z, a.z); a.w = fmaf(p, w.w, a.w);
}

// Repack conv/deconv weights to fp32 [ci][9][cout] (for fp32 kernels).
__global__ void repack_k(const float* __restrict__ src, float* __restrict__ dst,
                         int cout, int coutR, int cin, int flip, int deconv)
{
    int t = blockIdx.x * 256 + threadIdx.x;
    int tot = cin * 9 * cout;
    if (t >= tot) return;
    int co = t % cout; int k = (t / cout) % 9; int ci = t / (9 * cout);
    float v = 0.f;
    if (co < coutR) {
        int ks = flip ? 8 - k : k;
        v = deconv ? src[((size_t)ci * coutR + co) * 9 + ks]
                   : src[((size_t)co * cin + ci) * 9 + ks];
    }
    dst[t] = v;
}

// Prepack weights to fp16 hi/lo MFMA B-fragment order:
// 16B-block index = ((tap*C32 + c32)*NGtot + ng), within: lane*8 halves,
// element j: co = ng*16 + (lane&15), ci = c32*32 + ((lane>>4)&3)*8 + j.
// deconv=1: src is (cin, cout, 3,3), taps flipped.
__global__ void repackB16_k(const float* __restrict__ src, _Float16* __restrict__ bh,
                            _Float16* __restrict__ bl, int COUT, int CIN, int deconv)
{
    int t = blockIdx.x * 256 + threadIdx.x;
    int tot = 9 * CIN * COUT;
    if (t >= tot) return;
    int NGtot = COUT >> 4, C32 = CIN >> 5;
    int j = t & 7;
    int lane = (t >> 3) & 63;
    int blk = t >> 9;
    int ng = blk % NGtot; blk /= NGtot;
    int c32 = blk % C32;
    int tap = blk / C32;
    int co = ng * 16 + (lane & 15);
    int ci = c32 * 32 + ((lane >> 4) & 3) * 8 + j;
    float v = deconv ? src[((size_t)ci * COUT + co) * 9 + (8 - tap)]
                     : src[((size_t)co * CIN + ci) * 9 + tap];
    _Float16 h = (_Float16)v;
    _Float16 l = (_Float16)(v - (float)h);
    bh[t] = h; bl[t] = l;
}

// ================= MFMA 3x3 conv s1 p1 (fp16 hi/lo split) ===================
// Block: 128 positions (8 rows x 16 cols) x 64 co. Wave: 2 rows x 64 co.
// A staged per 32-ci chunk channels-last in LDS (one tile serves all 9 taps);
// B staged per (c32, ky-row) from fragment-packed global.
template<int CIN, bool RELU, bool ADDSELF>
__launch_bounds__(256, 3)
__global__ void mconv3s1_k(const float* __restrict__ in,
                           const _Float16* __restrict__ Bh, const _Float16* __restrict__ Bl,
                           const float* __restrict__ bias, float* __restrict__ out,
                           const float* __restrict__ addend,
                           int COUT, int H, int W)
{
    constexpr int C32 = CIN / 32;
    __shared__ __align__(16) unsigned char smBuf[53376];
    _Float16* AH = (_Float16*)smBuf;        // [10][18][40] = 7200 halves
    _Float16* AL = AH + 7200;               // 7200
    _Float16* BW = AL + 7200;               // [tapL3][ng4][hl2][lane64][8] = 12288
    float* smO = (float*)smBuf;             // [64][129] epilogue overlay

    const int tid = threadIdx.x;
    const int lane = tid & 63, yb = tid >> 6;
    const int n16 = lane & 15, q = lane >> 4;

    int b = blockIdx.x;
    const int chunks = COUT >> 6;
    const int coch = b % chunks; b /= chunks;
    const int tX = W >> 4; const int tx = b % tX; b /= tX;
    const int tY = H >> 3; const int ty = b % tY; const int n = b / tY;
    const int x0 = tx * 16, y0 = ty * 8;
    const int NGtot = COUT >> 4;
    const int ngbase = coch * 4, cobase = coch * 64;

    v4f acc[2][4];
#pragma unroll
    for (int ng = 0; ng < 4; ++ng) {
        float bb = bias[cobase + ng * 16 + n16];
        v4f bv = {bb, bb, bb, bb};
        acc[0][ng] = bv; acc[1][ng] = bv;
    }

    for (int c32 = 0; c32 < C32; ++c32) {
        __syncthreads();
        // ---- stage A (fp32 -> hi/lo fp16), 10x18 halo x 32 ci ----
        for (int u = tid; u < 5760; u += 256) {
            int ci = u / 180, rem = u - ci * 180;
            int yy = rem / 18, xx = rem - yy * 18;
            int gy = y0 - 1 + yy, gx = x0 - 1 + xx;
            float v = 0.f;
            if (gy >= 0 && gy < H && gx >= 0 && gx < W)
                v = in[(((size_t)n * CIN + c32 * 32 + ci) * H + gy) * W + gx];
            _Float16 h = (_Float16)v;
            _Float16 l = (_Float16)(v - (float)h);
            int a = (yy * 18 + xx) * 40 + ci;
            AH[a] = h; AL[a] = l;
        }
        for (int ky = 0; ky < 3; ++ky) {
            __syncthreads();
            // ---- stage B row: 3 taps x 4 ng x hi/lo, 1536 x 16B ----
            for (int u = tid; u < 1536; u += 256) {
                int lu = u & 63;
                int rest = u >> 6;
                int hl = rest & 1; rest >>= 1;
                int ng = rest & 3;
                int tapL = rest >> 2;
                const uint4* srcp = (const uint4*)(hl ? Bl : Bh);
                size_t sidx = (((size_t)(ky * 3 + tapL) * C32 + c32) * NGtot + ngbase + ng) * 64 + lu;
                ((uint4*)BW)[u] = srcp[sidx];
            }
            __syncthreads();
#pragma unroll
            for (int kx = 0; kx < 3; ++kx) {
                f16x8 aH[2], aL[2];
#pragma unroll
                for (int mg = 0; mg < 2; ++mg) {
                    int aoff = ((2 * yb + mg + ky) * 18 + n16 + kx) * 40 + q * 8;
                    aH[mg] = *(const f16x8*)&AH[aoff];
                    aL[mg] = *(const f16x8*)&AL[aoff];
                }
#pragma unroll
                for (int ng = 0; ng < 4; ++ng) {
                    int boff = ((kx * 4 + ng) * 2) * 512 + lane * 8;
                    f16x8 bH = *(const f16x8*)&BW[boff];
                    f16x8 bL = *(const f16x8*)&BW[boff + 512];
#pragma unroll
                    for (int mg = 0; mg < 2; ++mg) {
                        acc[mg][ng] = __builtin_amdgcn_mfma_f32_16x16x32_f16(aH[mg], bH, acc[mg][ng], 0, 0, 0);
                        acc[mg][ng] = __builtin_amdgcn_mfma_f32_16x16x32_f16(aL[mg], bH, acc[mg][ng], 0, 0, 0);
                        acc[mg][ng] = __builtin_amdgcn_mfma_f32_16x16x32_f16(aH[mg], bL, acc[mg][ng], 0, 0, 0);
                    }
                }
            }
        }
    }

    // ---- epilogue: LDS transpose -> coalesced stores, fused add/relu ----
    __syncthreads();
#pragma unroll
    for (int mg = 0; mg < 2; ++mg)
#pragma unroll
        for (int ng = 0; ng < 4; ++ng) {
            int p = (2 * yb + mg) * 16 + q * 4;
            int co = ng * 16 + n16;
#pragma unroll
            for (int r = 0; r < 4; ++r)
                smO[co * 129 + p + r] = acc[mg][ng][r];
        }
    __syncthreads();
    const size_t plane = (size_t)H * W;
    float* ob = out + ((size_t)n * COUT + cobase) * plane;
    const float* ab = ADDSELF ? addend + ((size_t)n * COUT + cobase) * plane : nullptr;
#pragma unroll
    for (int k = 0; k < 32; ++k) {
        int e = tid + 256 * k;
        int co = e >> 7, p = e & 127;
        int py = p >> 4, px = p & 15;
        size_t g = (size_t)co * plane + (size_t)(y0 + py) * W + x0 + px;
        float v = smO[co * 129 + p];
        if (ADDSELF) v += ab[g];
        if (RELU) v = fmaxf(v, 0.f);
        ob[g] = v;
    }
}

// ===================== 3x3 conv s2 p1 — fp32, 1x2 out x 32 co ===============
template<int CIN, int CB, bool RELU>
__launch_bounds__(256, 4)
__global__ void conv3s2_k(const float* __restrict__ in, const float* __restrict__ wp,
                          const float* __restrict__ bias, float* __restrict__ out,
                          int COUT, int Hin, int Win)
{
    constexpr int COC = 32;
    __shared__ float smIn[CB * 2178];           // 33 x 66
    __shared__ float smW[CB * 9 * COC];
    const int Hout = Hin >> 1, Wout = Win >> 1;
    const int tid = threadIdx.x;
    int b = blockIdx.x;
    const int chunks = COUT / COC;
    const int tX = Wout / 32, tY = Hout / 16;
    const int ch = b % chunks; b /= chunks;
    const int tx = b % tX; b /= tX;
    const int ty = b % tY; const int n = b / tY;
    const int cobase = ch * COC;
    const int r = tid >> 4, c = tid & 15;
    const int gy0 = ty * 32 - 1, gx0 = tx * 64 - 1;

    v4f acc[16];
#pragma unroll
    for (int g = 0; g < 8; ++g) {
        v4f bv = *(const v4f*)&bias[cobase + 4 * g];
        acc[g] = bv; acc[8 + g] = bv;
    }

    const size_t plane = (size_t)Hin * Win;
    const float* ip0 = in + (size_t)n * CIN * plane;
    const float* wp0 = wp + cobase;

    for (int ci0 = 0; ci0 < CIN; ci0 += CB) {
        __syncthreads();
        for (int idx = tid; idx < CB * 2178; idx += 256) {
            int ci = idx / 2178, rem = idx - ci * 2178;
            int rr = rem / 66, cc = rem - rr * 66;
            int gy = gy0 + rr, gx = gx0 + cc;
            float v = 0.f;
            if (gy >= 0 && gy < Hin && gx >= 0 && gx < Win)
                v = ip0[(size_t)(ci0 + ci) * plane + (size_t)gy * Win + gx];
            smIn[idx] = v;
        }
        for (int idx = tid; idx < CB * 9 * COC; idx += 256) {
            int q2 = idx >> 5, co = idx & 31;
            smW[idx] = wp0[((size_t)ci0 * 9 + q2) * COUT + co];
        }
        __syncthreads();

#pragma unroll 1
        for (int ci = 0; ci < CB; ++ci) {
            float p[15];
            const float* sp = &smIn[ci * 2178 + 2 * r * 66 + 4 * c];
#pragma unroll
            for (int i = 0; i < 3; ++i)
#pragma unroll
                for (int j = 0; j < 5; ++j)
                    p[i * 5 + j] = sp[i * 66 + j];
            const float* wrow = &smW[ci * 288];
#pragma unroll
            for (int k = 0; k < 9; ++k) {
                const int ky = k / 3, kx = k % 3;
#pragma unroll
                for (int g = 0; g < 8; ++g) {
                    v4f wv = *(const v4f*)&wrow[k * 32 + 4 * g];
                    fma4(acc[g],     p[ky * 5 + kx],     wv);
                    fma4(acc[8 + g], p[ky * 5 + kx + 2], wv);
                }
            }
        }
    }

    const size_t outPlane = (size_t)Hout * Wout;
    const int oy = ty * 16 + r, ox = tx * 32 + 2 * c;
    float* op = out + ((size_t)n * COUT + cobase) * outPlane + (size_t)oy * Wout + ox;
#pragma unroll
    for (int g = 0; g < 8; ++g)
#pragma unroll
        for (int e = 0; e < 4; ++e) {
            float v0 = acc[g][e], v1 = acc[8 + g][e];
            if (RELU) { v0 = fmaxf(v0, 0.f); v1 = fmaxf(v1, 0.f); }
            *(float2*)&op[(size_t)(4 * g + e) * outPlane] = make_float2(v0, v1);
        }
}

// =========== ConvTranspose k3 s2 p1 op1 — fp32, 2 quads/thread ==============
template<int CIN, int CB, int COC, bool RELU>
__launch_bounds__(256, 3)
__global__ void deconv2_k(const float* __restrict__ in, const float* __restrict__ wp,
                          const float* __restrict__ bias, float* __restrict__ out,
                          int COUTR, int COUTP, int Hin, int Win)
{
    constexpr int RW = 33, RH = 17;
    __shared__ float smIn[CB * RH * RW];
    __shared__ float smW[CB * 9 * COC];
    const int Wout = Win * 2;
    const int tid = threadIdx.x;
    int b = blockIdx.x;
    const int chunks = COUTP / COC;
    const int qTX = Win / 32, qTY = Hin / 16;
    const int ch = b % chunks; b /= chunks;
    const int qtx = b % qTX; b /= qTX;
    const int qty = b % qTY; const int n = b / qTY;
    const int cobase = ch * COC;
    const int tqy = tid >> 4, tqx = tid & 15;
    const int qby = qty * 16, qbx = qtx * 32;

    v4f acc[8 * COC / 4];
#pragma unroll
    for (int g = 0; g < COC / 4; ++g) {
        v4f bv;
#pragma unroll
        for (int e = 0; e < 4; ++e)
            bv[e] = (cobase + 4 * g + e < COUTR) ? bias[cobase + 4 * g + e] : 0.f;
#pragma unroll
        for (int pt = 0; pt < 8; ++pt) acc[pt * (COC / 4) + g] = bv;
    }

    const size_t plane = (size_t)Hin * Win;
    const float* ip0 = in + (size_t)n * CIN * plane;
    const float* wp0 = wp + cobase;

    for (int ci0 = 0; ci0 < CIN; ci0 += CB) {
        __syncthreads();
        for (int idx = tid; idx < CB * RH * RW; idx += 256) {
            int ci = idx / (RH * RW), rem = idx - ci * (RH * RW);
            int rr = rem / RW, cc = rem - rr * RW;
            int gy = qby + rr, gx = qbx + cc;
            float v = 0.f;
            if (gy < Hin && gx < Win)
                v = ip0[(size_t)(ci0 + ci) * plane + (size_t)gy * Win + gx];
            smIn[idx] = v;
        }
        for (int idx = tid; idx < CB * 9 * COC; idx += 256) {
            int q2 = idx / COC, co = idx % COC;
            smW[idx] = wp0[((size_t)ci0 * 9 + q2) * COUTP + co];
        }
        __syncthreads();

#pragma unroll 1
        for (int ci = 0; ci < CB; ++ci) {
            float p[6];
            const float* sp = &smIn[ci * RH * RW + tqy * RW + 2 * tqx];
#pragma unroll
            for (int i = 0; i < 2; ++i)
#pragma unroll
                for (int j = 0; j < 3; ++j)
                    p[i * 3 + j] = sp[i * RW + j];
            const float* wrow = &smW[ci * 9 * COC];
#pragma unroll
            for (int k = 0; k < 9; ++k) {
                const int ky = k / 3, kx = k % 3;
                const int dy = (ky == 1) ? 0 : 1, iy = (ky == 0) ? 1 : 0;
                const int dx = (kx == 1) ? 0 : 1, ix = (kx == 0) ? 1 : 0;
#pragma unroll
                for (int g = 0; g < COC / 4; ++g) {
                    v4f wv = *(const v4f*)&wrow[k * COC + 4 * g];
                    fma4(acc[(0 + dy * 2 + dx) * (COC / 4) + g], p[iy * 3 + ix],     wv);
                    fma4(acc[(4 + dy * 2 + dx) * (COC / 4) + g], p[iy * 3 + ix + 1], wv);
                }
            }
        }
    }

    const size_t oPlane = (size_t)(Hin * 2) * Wout;
    const int oy = 2 * (qby + tqy), ox = 2 * (qbx + 2 * tqx);
#pragma unroll
    for (int g = 0; g < COC / 4; ++g)
#pragma unroll
        for (int e = 0; e < 4; ++e) {
            int cch = cobase + 4 * g + e;
            if (cch >= COUTR) break;
            float* op = out + ((size_t)n * COUTR + cch) * oPlane + (size_t)oy * Wout + ox;
#pragma unroll
            for (int a2 = 0; a2 < 2; ++a2) {
                float u0 = acc[(0 + a2 * 2 + 0) * (COC / 4) + g][e];
                float u1 = acc[(0 + a2 * 2 + 1) * (COC / 4) + g][e];
                float u2 = acc[(4 + a2 * 2 + 0) * (COC / 4) + g][e];
                float u3 = acc[(4 + a2 * 2 + 1) * (COC / 4) + g][e];
                if (RELU) { u0 = fmaxf(u0, 0.f); u1 = fmaxf(u1, 0.f);
                            u2 = fmaxf(u2, 0.f); u3 = fmaxf(u3, 0.f); }
                *(float4*)&op[(size_t)a2 * Wout] = make_float4(u0, u1, u2, u3);
            }
        }
}

// ===================== 1x1 conv stride S — 1 pos/thread, 32 co ==============
template<int CIN, int S, bool RELU>
__launch_bounds__(256, 4)
__global__ void conv1x1_k(const float* __restrict__ in, const float* __restrict__ w,
                          const float* __restrict__ bias, float* __restrict__ out,
                          int COUT, int Hin, int Win, int Hout, int Wout)
{
    constexpr int COC = 32;
    __shared__ float smW[CIN * COC];
    const int tid = threadIdx.x;
    int b = blockIdx.x;
    const int chunks = COUT / COC;
    const int spB = (Hout * Wout) / 256;
    const int ch = b % chunks; b /= chunks;
    const int sb = b % spB; const int n = b / spB;
    const int cobase = ch * COC;

    for (int idx = tid; idx < CIN * COC; idx += 256) {
        int ci = idx / COC, co = idx - ci * COC;
        smW[idx] = w[(size_t)(cobase + co) * CIN + ci];
    }
    __syncthreads();

    const int pos = sb * 256 + tid;
    const int oy = pos / Wout, ox = pos - oy * Wout;

    v4f acc[8];
#pragma unroll
    for (int g = 0; g < 8; ++g) acc[g] = *(const v4f*)&bias[cobase + 4 * g];

    const size_t inPlane = (size_t)Hin * Win;
    const float* ip = in + (size_t)n * CIN * inPlane + (size_t)(oy * S) * Win + (size_t)(ox * S);
#pragma unroll 1
    for (int ci = 0; ci < CIN; ++ci) {
        float v = ip[(size_t)ci * inPlane];
#pragma unroll
        for (int g = 0; g < 8; ++g)
            fma4(acc[g], v, *(const v4f*)&smW[ci * COC + 4 * g]);
    }
    const size_t outPlane = (size_t)Hout * Wout;
    float* op = out + ((size_t)n * COUT + cobase) * outPlane + pos;
#pragma unroll
    for (int g = 0; g < 8; ++g)
#pragma unroll
        for (int e = 0; e < 4; ++e) {
            float v = acc[g][e];
            if (RELU) v = fmaxf(v, 0.f);
            op[(size_t)(4 * g + e) * outPlane] = v;
        }
}

// ============================== quantize ===================================
__launch_bounds__(256)
__global__ void quantize_k(const float* __restrict__ h, const float* __restrict__ cb,
                           float* __restrict__ q)
{
    __shared__ float cn[512];
    __shared__ float cbl[128 * 64];
    const int tid = threadIdx.x;

    for (int i = tid; i < 512; i += 256) {
        float s = 0.f;
#pragma unroll
        for (int j = 0; j < 64; ++j) { float v = cb[i * 64 + j]; s = fmaf(v, v, s); }
        cn[i] = s;
    }

    const int t = blockIdx.x * 256 + tid;
    const int n = t >> 12, rem = t & 4095;
    const float* hp = h + (size_t)n * 64 * 4096 + rem;
    float e[64];
#pragma unroll
    for (int j = 0; j < 64; ++j) e[j] = hp[(size_t)j * 4096];

    float best = 3.4e38f; int bi = 0;
    for (int chn = 0; chn < 4; ++chn) {
        __syncthreads();
        const float4* src = reinterpret_cast<const float4*>(cb + chn * 128 * 64);
        float4* dst = reinterpret_cast<float4*>(cbl);
        for (int i = tid; i < 128 * 64 / 4; i += 256) dst[i] = src[i];
        __syncthreads();
        for (int c = 0; c < 128; ++c) {
            float dot = 0.f;
#pragma unroll
            for (int j = 0; j < 64; ++j) dot = fmaf(e[j], cbl[c * 64 + j], dot);
            float d = cn[chn * 128 + c] - 2.f * dot;
            if (d < best) { best = d; bi = chn * 128 + c; }
        }
    }

    const float* crow = cb + (size_t)bi * 64;
    float* qp = q + (size_t)n * 64 * 4096 + rem;
#pragma unroll
    for (int j = 0; j < 64; ++j) qp[(size_t)j * 4096] = crow[j];
}

extern "C" void kernel_launch(void* const* d_in, const int* in_sizes, int n_in,
                              void* d_out, int out_size, void* d_ws, size_t ws_size,
                              hipStream_t stream)
{
    const float* x    = (const float*)d_in[0];
    const float* e0w1 = (const float*)d_in[1];  const float* e0b1 = (const float*)d_in[2];
    const float* e0w2 = (const float*)d_in[3];  const float* e0b2 = (const float*)d_in[4];
    const float* e0wd = (const float*)d_in[5];  const float* e0bd = (const float*)d_in[6];
    const float* e1w1 = (const float*)d_in[7];  const float* e1b1 = (const float*)d_in[8];
    const float* e1w2 = (const float*)d_in[9];  const float* e1b2 = (const float*)d_in[10];
    const float* e1wd = (const float*)d_in[11]; const float* e1bd = (const float*)d_in[12];
    const float* e2w1 = (const float*)d_in[13]; const float* e2b1 = (const float*)d_in[14];
    const float* e2w2 = (const float*)d_in[15]; const float* e2b2 = (const float*)d_in[16];
    const float* e2wd = (const float*)d_in[17]; const float* e2bd = (const float*)d_in[18];
    const float* d0w  = (const float*)d_in[19]; const float* d0b  = (const float*)d_in[20];
    const float* d1w  = (const float*)d_in[21]; const float* d1b  = (const float*)d_in[22];
    const float* d2w  = (const float*)d_in[23]; const float* d2b  = (const float*)d_in[24];
    const float* cb   = (const float*)d_in[25];
    float* out = (float*)d_out;
    float* ws  = (float*)d_ws;

    // ---- packs in d_out slack (d_out only written by the final dec2) ----
    float* P_e0w1 = out + 0;            // fp32 pack, 1728
    float* P_d1w  = out + 1728;         // fp32 pack, 73728
    // fp16 fragment packs (as _Float16*, all offsets 16B-aligned):
    _Float16* Bh_e0c2 = (_Float16*)(out + 77760);
    _Float16* Bl_e0c2 = (_Float16*)(out + 96192);
    _Float16* Bh_e1c2 = (_Float16*)(out + 114624);
    _Float16* Bl_e1c2 = (_Float16*)(out + 188352);
    _Float16* Bh_e2c1 = (_Float16*)(out + 262080);
    _Float16* Bl_e2c1 = (_Float16*)(out + 298944);
    _Float16* Bh_e2c2 = (_Float16*)(out + 335808);
    _Float16* Bl_e2c2 = (_Float16*)(out + 354240);
    _Float16* Bh_d0   = (_Float16*)(out + 372672);
    _Float16* Bl_d0   = (_Float16*)(out + 409536);
    float* P_e1w1 = out + 446400;       // fp32 pack, 73728
    float* P_d2w  = ws + 50405376;      // fp32 pack; written after S1 is dead

    // ---- ws activation layout (floats), liveness-planned ----
    float* S0 = ws;                     // [0, 33.5M)  enc0 out
    float* T1 = ws + 33554432;          // enc0 conv1 out (full batch)
    float* T3 = ws + 33554432;          // enc1 conv1 out
    float* S1 = ws + 50331648;          // enc1 out
    float* S2 = ws;                     // enc2 out
    float* T5 = ws + 8388608;
    float* Q  = ws + 16777216;
    float* D0 = ws + 33554432;          // dec0 out
    float* D1 = ws;                     // dec1 out

    dim3 blk(256);
    auto rp = [&](const float* src, float* dst, int cout, int coutR, int cin, int flip, int dec) {
        int tot = cin * 9 * cout;
        repack_k<<<dim3((tot + 255) / 256), blk, 0, stream>>>(src, dst, cout, coutR, cin, flip, dec);
    };
    auto rpB = [&](const float* src, _Float16* bh, _Float16* bl, int cout, int cin, int dec) {
        int tot = 9 * cin * cout;
        repackB16_k<<<dim3((tot + 255) / 256), blk, 0, stream>>>(src, bh, bl, cout, cin, dec);
    };

    rp(e0w1, P_e0w1, 64, 64, 3, 0, 0);
    rp(e1w1, P_e1w1, 128, 128, 64, 0, 0);
    rp(d1w,  P_d1w, 64, 64, 128, 0, 1);
    rpB(e0w2, Bh_e0c2, Bl_e0c2, 64, 64, 0);
    rpB(e1w2, Bh_e1c2, Bl_e1c2, 128, 128, 0);
    rpB(e2w1, Bh_e2c1, Bl_e2c1, 64, 128, 0);
    rpB(e2w2, Bh_e2c2, Bl_e2c2, 64, 64, 0);
    rpB(d0w,  Bh_d0,   Bl_d0,   128, 64, 1);   // ConvT s1 == flipped conv

    // --- enc0 (3 -> 64, s2): 256 -> 128 ---
    conv1x1_k<3, 2, false><<<dim3(32 * 64 * 2), blk, 0, stream>>>(
        x, e0wd, e0bd, S0, 64, 256, 256, 128, 128);
    conv3s2_k<3, 3, true><<<dim3(32 * 8 * 4 * 2), blk, 0, stream>>>(
        x, P_e0w1, e0b1, T1, 64, 256, 256);
    mconv3s1_k<64, true, true><<<dim3(32 * 16 * 8 * 1), blk, 0, stream>>>(
        T1, Bh_e0c2, Bl_e0c2, e0b2, S0, S0, 64, 128, 128);

    // --- enc1 (64 -> 128, s2): 128 -> 64 ---
    conv1x1_k<64, 2, false><<<dim3(32 * 16 * 4), blk, 0, stream>>>(
        S0, e1wd, e1bd, S1, 128, 128, 128, 64, 64);
    conv3s2_k<64, 4, true><<<dim3(32 * 4 * 2 * 4), blk, 0, stream>>>(
        S0, P_e1w1, e1b1, T3, 128, 128, 128);
    mconv3s1_k<128, true, true><<<dim3(32 * 8 * 4 * 2), blk, 0, stream>>>(
        T3, Bh_e1c2, Bl_e1c2, e1b2, S1, S1, 128, 64, 64);

    // --- enc2 (128 -> 64, s1) ---
    conv1x1_k<128, 1, false><<<dim3(32 * 16 * 2), blk, 0, stream>>>(
        S1, e2wd, e2bd, S2, 64, 64, 64, 64, 64);
    mconv3s1_k<128, true, false><<<dim3(32 * 8 * 4 * 1), blk, 0, stream>>>(
        S1, Bh_e2c1, Bl_e2c1, e2b1, T5, nullptr, 64, 64, 64);
    rp(d2w, P_d2w, 4, 3, 64, 0, 1);             // S1 dead after the two reads above
    mconv3s1_k<64, true, true><<<dim3(32 * 8 * 4 * 1), blk, 0, stream>>>(
        T5, Bh_e2c2, Bl_e2c2, e2b2, S2, S2, 64, 64, 64);

    // --- quantize ---
    quantize_k<<<dim3(512), blk, 0, stream>>>(S2, cb, Q);

    // --- dec0: ConvT s1 (64 -> 128) as flipped conv, ReLU ---
    mconv3s1_k<64, true, false><<<dim3(32 * 8 * 4 * 2), blk, 0, stream>>>(
        Q, Bh_d0, Bl_d0, d0b, D0, nullptr, 128, 64, 64);

    // --- dec1: ConvT s2 (128 -> 64), ReLU: 64 -> 128 ---
    deconv2_k<128, 4, 16, true><<<dim3(32 * 2 * 4 * 4), blk, 0, stream>>>(
        D0, P_d1w, d1b, D1, 64, 64, 64, 64);

    // --- dec2: ConvT s2 (64 -> 3): 128 -> 256 ---
    deconv2_k<64, 8, 4, false><<<dim3(32 * 4 * 8), blk, 0, stream>>>(
        D1, P_d2w, d2b, out, 3, 4, 128, 128);
}